// Round 6
// baseline (300.710 us; speedup 1.0000x reference)
//
#include <hip/hip_runtime.h>

// CRF NLL on MI355X — round 6 (round-5 design, compile fix).
// MFMA chain with zero inter-step data movement.
// Form: D = A·B with A = E^T stationary (f16 frags, 16 chains per wave as N).
// v_mfma_f32_16x16x16f16: D layout (row=4*quad+reg, col=lane&15) == B layout
// (k=4*quad+elem, n=lane&15)  =>  step t's D (after em-mul + cvt) IS step
// t+1's B operand. No LDS, no barriers, no shuffles in the K-loop.
// 4 chain blocks (1 wave, 16 chains each) + 1 gold block; combiner kernel.

#define BB 64
#define SS 512
#define TT 64
#define START_TAG 62
#define END_TAG 63
#define LOG2E_F 1.44269504088896340736f
#define LN2_F 0.69314718055994530942f

typedef float v2f __attribute__((ext_vector_type(2)));
typedef float v4f __attribute__((ext_vector_type(4)));
typedef _Float16 h4 __attribute__((ext_vector_type(4)));
typedef __fp16 f16x2 __attribute__((ext_vector_type(2)));

union H4u { h4 v; struct { f16x2 lo, hi; } p; };

template <bool MASKED>
__device__ __forceinline__ void crf_step(int T, const h4 (&A)[4][4], h4 (&Bf)[4],
                                         v4f (&FR)[4], const float* fbl,
                                         int Lc, int& esum, int& e_pend) {
    bool live = !MASKED || (T < Lc);
    int e_use = live ? e_pend : 0;
    esum += e_use;
    float ef = (float)e_use;

    // ---- matvec: D[j][c] = sum_i E^T[j][i] * q[i][c], K=64 as 4 K-tiles ----
    v4f D[4];
    v4f z = {0.f, 0.f, 0.f, 0.f};
#pragma unroll
    for (int mt = 0; mt < 4; ++mt) {
        v4f a0 = __builtin_amdgcn_mfma_f32_16x16x16f16(A[mt][0], Bf[0], z, 0, 0, 0);
        a0     = __builtin_amdgcn_mfma_f32_16x16x16f16(A[mt][1], Bf[1], a0, 0, 0, 0);
        v4f a1 = __builtin_amdgcn_mfma_f32_16x16x16f16(A[mt][2], Bf[2], z, 0, 0, 0);
        a1     = __builtin_amdgcn_mfma_f32_16x16x16f16(A[mt][3], Bf[3], a1, 0, 0, 0);
        D[mt] = a0 + a1;
    }

    // ---- emission * renorm: qn = D * exp2(f*log2e - e_use)  (fp32) ----
    v4f qn[4];
#pragma unroll
    for (int mt = 0; mt < 4; ++mt) {
        v4f f4 = FR[mt];
        v4f em;
        em.x = __builtin_amdgcn_exp2f(__builtin_fmaf(f4.x, LOG2E_F, -ef));
        em.y = __builtin_amdgcn_exp2f(__builtin_fmaf(f4.y, LOG2E_F, -ef));
        em.z = __builtin_amdgcn_exp2f(__builtin_fmaf(f4.z, LOG2E_F, -ef));
        em.w = __builtin_amdgcn_exp2f(__builtin_fmaf(f4.w, LOG2E_F, -ef));
        qn[mt] = D[mt] * em;
    }

    // ---- refill this FR buffer with f(T+2) (consumed 2 steps from now) ----
    {
        int tn = T + 2; tn = tn < SS ? tn : SS - 1;
        const float* fp = fbl + (size_t)tn * TT;
#pragma unroll
        for (int mt = 0; mt < 4; ++mt) FR[mt] = *(const v4f*)(fp + 16 * mt);
    }

    // ---- B update: D reg r of tile mt == B elem jj of K-tile kt (kt=mt, jj=r) ----
#pragma unroll
    for (int mt = 0; mt < 4; ++mt) {
        H4u u;
        u.p.lo = __builtin_amdgcn_cvt_pkrtz(qn[mt].x, qn[mt].y);
        u.p.hi = __builtin_amdgcn_cvt_pkrtz(qn[mt].z, qn[mt].w);
        h4 nv = u.v;
        if (MASKED) nv = live ? nv : Bf[mt];   // freeze finished chains
        Bf[mt] = nv;
    }

    // ---- delayed renorm: per-chain max exponent, consumed next step ----
    v4f m01 = __builtin_elementwise_max(qn[0], qn[1]);
    v4f m23 = __builtin_elementwise_max(qn[2], qn[3]);
    v4f m4  = __builtin_elementwise_max(m01, m23);
    float mm = fmaxf(fmaxf(m4.x, m4.y), fmaxf(m4.z, m4.w));
    mm = fmaxf(mm, __shfl_xor(mm, 16, 64));
    mm = fmaxf(mm, __shfl_xor(mm, 32, 64));
    e_pend = (int)((__float_as_uint(mm) >> 23) & 255u) - 127;
}

__global__ __launch_bounds__(256, 1)
void crf_main(const float* __restrict__ feats, const float* __restrict__ trans,
              const int* __restrict__ mask, const int* __restrict__ tags,
              float* __restrict__ ws) {
    const int blk = blockIdx.x;
    const int tid = threadIdx.x;

    if (blk < 4) {
        if (tid >= 64) return;
        const int l = tid;
        const int c16 = l & 15;         // chain-in-block == MFMA n/col == A's m
        const int quad = l >> 4;
        const int cg = blk * 16 + c16;  // global chain

        // ---- A = E^T stationary fragments (f16) ----
        h4 A[4][4];
#pragma unroll
        for (int mt = 0; mt < 4; ++mt)
#pragma unroll
            for (int kt = 0; kt < 4; ++kt) {
                h4 a;
#pragma unroll
                for (int e = 0; e < 4; ++e) {
                    int i = 4 * quad + e + 16 * kt;   // input tag
                    int j = c16 + 16 * mt;            // output tag
                    a[e] = (_Float16)expf(trans[i * TT + j]);
                }
                A[mt][kt] = a;
            }

        // ---- per-chain length Lc ----
        const int* mp = mask + cg * SS + quad * 128;
        int ls = 0;
#pragma unroll
        for (int k = 0; k < 32; ++k) {
            int4 m4i = ((const int4*)mp)[k];
            ls += m4i.x + m4i.y + m4i.z + m4i.w;
        }
        ls += __shfl_xor(ls, 16, 64);
        ls += __shfl_xor(ls, 32, 64);
        const int Lc = ls;
        int lmin = Lc, lmax = Lc;
#pragma unroll
        for (int m = 1; m < 64; m <<= 1) {
            lmin = min(lmin, __shfl_xor(lmin, m, 64));
            lmax = max(lmax, __shfl_xor(lmax, m, 64));
        }

        // ---- init: q0 = exp(f0 + trans[START] - M0) directly into B frags ----
        const float* fbl = feats + (size_t)cg * SS * TT + 4 * quad;
        v4f p0[4];
        float M0 = -1e30f;
#pragma unroll
        for (int kt = 0; kt < 4; ++kt) {
            v4f f4 = *(const v4f*)(fbl + 16 * kt);  // t = 0
            v4f ts4 = *(const v4f*)(trans + START_TAG * TT + 4 * quad + 16 * kt);
            v4f p = f4 + ts4;
            p0[kt] = p;
            M0 = fmaxf(M0, fmaxf(fmaxf(p.x, p.y), fmaxf(p.z, p.w)));
        }
        M0 = fmaxf(M0, __shfl_xor(M0, 16, 64));
        M0 = fmaxf(M0, __shfl_xor(M0, 32, 64));
        h4 Bf[4];
#pragma unroll
        for (int kt = 0; kt < 4; ++kt) {
            v4f p = p0[kt];
            float q0 = __builtin_amdgcn_exp2f((p.x - M0) * LOG2E_F);
            float q1 = __builtin_amdgcn_exp2f((p.y - M0) * LOG2E_F);
            float q2 = __builtin_amdgcn_exp2f((p.z - M0) * LOG2E_F);
            float q3 = __builtin_amdgcn_exp2f((p.w - M0) * LOG2E_F);
            H4u u;
            u.p.lo = __builtin_amdgcn_cvt_pkrtz(q0, q1);
            u.p.hi = __builtin_amdgcn_cvt_pkrtz(q2, q3);
            Bf[kt] = u.v;
        }

        // ---- f prefetch: fr0 <- f(1), fr1 <- f(2) ----
        v4f fr0[4], fr1[4];
#pragma unroll
        for (int mt = 0; mt < 4; ++mt) {
            fr0[mt] = *(const v4f*)(fbl + 1 * TT + 16 * mt);
            fr1[mt] = *(const v4f*)(fbl + 2 * TT + 16 * mt);
        }

        int esum = 0, e_pend = 0;
        int t = 1;
        const int T1 = (lmin - 1) & ~1;   // even count of unmasked steps
        for (; t + 1 <= T1; t += 2) {
            crf_step<false>(t,     A, Bf, fr0, fbl, Lc, esum, e_pend);
            crf_step<false>(t + 1, A, Bf, fr1, fbl, Lc, esum, e_pend);
        }
        for (; t < lmax; t += 2) {        // may overshoot by 1 step: fully frozen, harmless
            crf_step<true>(t,     A, Bf, fr0, fbl, Lc, esum, e_pend);
            crf_step<true>(t + 1, A, Bf, fr1, fbl, Lc, esum, e_pend);
        }

        // ---- finalize: dot(q_{L-1}, Eend), per-chain log ----
        float acc = 0.f;
#pragma unroll
        for (int kt = 0; kt < 4; ++kt)
#pragma unroll
            for (int e = 0; e < 4; ++e) {
                int i = 4 * quad + e + 16 * kt;
                acc += (float)Bf[kt][e] * expf(trans[i * TT + END_TAG]);
            }
        acc += __shfl_xor(acc, 16, 64);
        acc += __shfl_xor(acc, 32, 64);
        float val = logf(acc) + (float)esum * LN2_F + M0;  // same on 4 quad lanes
#pragma unroll
        for (int m = 1; m < 64; m <<= 1) val += __shfl_xor(val, m, 64);
        if (l == 0) ws[blk] = 0.25f * val;   // each chain counted 4x
    } else {
        // ---- gold score block: 4 waves x 16 chains; lane=(chain, t-quarter) ----
        const int w = tid >> 6, l = tid & 63;
        const int c = w * 16 + (l & 15);
        const int quad = l >> 4;

        const int* mp = mask + c * SS + quad * 128;
        int ls = 0;
#pragma unroll
        for (int k = 0; k < 32; ++k) {
            int4 m4i = ((const int4*)mp)[k];
            ls += m4i.x + m4i.y + m4i.z + m4i.w;
        }
        ls += __shfl_xor(ls, 16, 64);
        ls += __shfl_xor(ls, 32, 64);
        const int Lc = ls;

        const int* tb = tags + c * SS;
        const float* fc = feats + (size_t)c * SS * TT;
        float g = 0.f;
        const int t0 = quad * 128;
#pragma unroll 8
        for (int k = 0; k < 128; ++k) {
            int t = t0 + k;
            int cur = tb[t];
            int prev = (t == 0) ? START_TAG : tb[t - 1];
            if (t < Lc) g += fc[(size_t)t * TT + cur] + trans[prev * TT + cur];
        }
        if (quad == 0) g += trans[tb[Lc - 1] * TT + END_TAG];
#pragma unroll
        for (int m = 1; m < 64; m <<= 1) g += __shfl_xor(g, m, 64);
        if (l == 0) ws[4 + w] = -g;
    }
}

__global__ void crf_combine(const float* __restrict__ ws, float* __restrict__ out) {
    float s = 0.f;
#pragma unroll
    for (int i = 0; i < 8; ++i) s += ws[i];
    out[0] = s;
}

extern "C" void kernel_launch(void* const* d_in, const int* in_sizes, int n_in,
                              void* d_out, int out_size, void* d_ws, size_t ws_size,
                              hipStream_t stream) {
    const float* feats = (const float*)d_in[0];
    const float* trans = (const float*)d_in[1];
    const int*   mask  = (const int*)d_in[2];
    const int*   tags  = (const int*)d_in[3];
    float* ws  = (float*)d_ws;
    float* out = (float*)d_out;

    crf_main<<<dim3(5), dim3(256), 0, stream>>>(feats, trans, mask, tags, ws);
    crf_combine<<<dim3(1), dim3(1), 0, stream>>>(ws, out);
}

// Round 8
// 161.118 us; speedup vs baseline: 1.8664x; 1.8664x over previous
//
#include <hip/hip_runtime.h>

// CRF NLL on MI355X — round 8: chunked matrix-product scan (round-7 + fixes).
// x_{L-1} = (Prod_t diag(e^{f_t}) E^T) x_0; C=8 chunks of 64 steps per chain
// computed in parallel as 64x64 f16 partial products (MFMA zero-copy D->B).
// FIX vs r7: combine applies per-column exponents via max-shift
// (y_n = x_n * 2^{e_n - emax}), never materializing 2^{e} — r7 made inf*0=NaN.
// Fallback: if ws_size < needed, run the round-4 proven kernel instead.

#define SS 512
#define TT 64
#define CC 8
#define KCH 64
#define START_TAG 62
#define END_TAG 63
#define LOG2E_F 1.44269504088896340736f
#define LN2_F 0.69314718055994530942f

#define WS_ECOL_OFF 4194304
#define WS_GOLD_OFF 4325376
#define WS_NEEDED   (WS_GOLD_OFF + 64)

typedef float v2f __attribute__((ext_vector_type(2)));
typedef float v4f __attribute__((ext_vector_type(4)));
typedef _Float16 h4 __attribute__((ext_vector_type(4)));
typedef __fp16 c2 __attribute__((ext_vector_type(2)));
union H4u { h4 v; struct { c2 lo, hi; } p; };

// ============================ chunked path ============================

__device__ __forceinline__ void chunk_step(const h4 (&A)[4][4], h4 (&B)[4],
                                           v4f (&FR)[4], const float* fb, int T,
                                           int& esum, int& esc) {
    v4f z = {0.f, 0.f, 0.f, 0.f};
    v4f D[4];
#pragma unroll
    for (int mt = 0; mt < 4; ++mt) {
        v4f a = __builtin_amdgcn_mfma_f32_16x16x16f16(A[mt][0], B[0], z, 0, 0, 0);
        a = __builtin_amdgcn_mfma_f32_16x16x16f16(A[mt][1], B[1], a, 0, 0, 0);
        a = __builtin_amdgcn_mfma_f32_16x16x16f16(A[mt][2], B[2], a, 0, 0, 0);
        a = __builtin_amdgcn_mfma_f32_16x16x16f16(A[mt][3], B[3], a, 0, 0, 0);
        D[mt] = a;
    }
    float escF = (float)esc;
    esum += esc;
    v4f qn[4];
#pragma unroll
    for (int mt = 0; mt < 4; ++mt) {
        v4f f4 = FR[mt];
        v4f em;
        em.x = __builtin_amdgcn_exp2f(__builtin_fmaf(f4.x, LOG2E_F, -escF));
        em.y = __builtin_amdgcn_exp2f(__builtin_fmaf(f4.y, LOG2E_F, -escF));
        em.z = __builtin_amdgcn_exp2f(__builtin_fmaf(f4.z, LOG2E_F, -escF));
        em.w = __builtin_amdgcn_exp2f(__builtin_fmaf(f4.w, LOG2E_F, -escF));
        qn[mt] = D[mt] * em;
    }
    {
        int tn = T + 2; tn = tn < SS ? tn : SS - 1;
        const float* fp = fb + (size_t)tn * TT;
#pragma unroll
        for (int mt = 0; mt < 4; ++mt) FR[mt] = *(const v4f*)(fp + 16 * mt);
    }
#pragma unroll
    for (int mt = 0; mt < 4; ++mt) {
        H4u u;
        u.p.lo = __builtin_amdgcn_cvt_pkrtz(qn[mt].x, qn[mt].y);
        u.p.hi = __builtin_amdgcn_cvt_pkrtz(qn[mt].z, qn[mt].w);
        B[mt] = u.v;
    }
    v4f m01 = __builtin_elementwise_max(qn[0], qn[1]);
    v4f m23 = __builtin_elementwise_max(qn[2], qn[3]);
    v4f m4 = __builtin_elementwise_max(m01, m23);
    float mm = fmaxf(fmaxf(m4.x, m4.y), fmaxf(m4.z, m4.w));
    mm = fmaxf(mm, __shfl_xor(mm, 16, 64));
    mm = fmaxf(mm, __shfl_xor(mm, 32, 64));
    esc = (int)((__float_as_uint(mm) >> 23) & 255u) - 127;
}

__global__ __launch_bounds__(256, 1)
void crf_chunks(const float* __restrict__ feats, const float* __restrict__ trans,
                const int* __restrict__ mask, const int* __restrict__ tags,
                float* __restrict__ out, unsigned short* __restrict__ Pg,
                int* __restrict__ Eg, float* __restrict__ Gg) {
    __shared__ __align__(16) _Float16 lds[TT * TT];
    const int blk = blockIdx.x;
    const int tid = threadIdx.x;

    if (blk < 64 * CC) {
        const int chain = blk >> 3, c = blk & 7;
        const int w = tid >> 6, l = tid & 63;
        const int n16 = l & 15, q = l >> 4;
        const int ncol = 16 * w + n16;

        h4 A[4][4];
#pragma unroll
        for (int mt = 0; mt < 4; ++mt)
#pragma unroll
            for (int ks = 0; ks < 4; ++ks) {
                h4 a;
#pragma unroll
                for (int e = 0; e < 4; ++e)
                    a[e] = (_Float16)expf(trans[(16 * ks + 4 * q + e) * TT + 16 * mt + n16]);
                A[mt][ks] = a;
            }

        const int* mp = mask + chain * SS;
        int msum = 0;
#pragma unroll
        for (int k = 0; k < 8; ++k) msum += mp[k * 64 + l];
#pragma unroll
        for (int s_ = 1; s_ < 64; s_ <<= 1) msum += __shfl_xor(msum, s_, 64);
        const int L = msum;

        const int t0 = 1 + KCH * c;
        int nlive = (L - 1) - KCH * c;
        nlive = nlive < 0 ? 0 : (nlive > KCH ? KCH : nlive);

        h4 B[4];
#pragma unroll
        for (int ks = 0; ks < 4; ++ks) {
            h4 b;
#pragma unroll
            for (int j = 0; j < 4; ++j)
                b[j] = (_Float16)((16 * ks + 4 * q + j == ncol) ? 1.f : 0.f);
            B[ks] = b;
        }

        const float* fb = feats + (size_t)chain * SS * TT + 4 * q;
        v4f fr0[4], fr1[4];
        {
            int tp0 = t0 < SS ? t0 : SS - 1;
            int tp1 = t0 + 1 < SS ? t0 + 1 : SS - 1;
#pragma unroll
            for (int mt = 0; mt < 4; ++mt) {
                fr0[mt] = *(const v4f*)(fb + (size_t)tp0 * TT + 16 * mt);
                fr1[mt] = *(const v4f*)(fb + (size_t)tp1 * TT + 16 * mt);
            }
        }

        int esum = 0, esc = 0;
        int step = 0;
        for (; step + 1 < nlive; step += 2) {
            chunk_step(A, B, fr0, fb, t0 + step, esum, esc);
            chunk_step(A, B, fr1, fb, t0 + step + 1, esum, esc);
        }
        if (step < nlive) chunk_step(A, B, fr0, fb, t0 + step, esum, esc);

#pragma unroll
        for (int ks = 0; ks < 4; ++ks)
#pragma unroll
            for (int j = 0; j < 4; ++j)
                lds[(16 * ks + 4 * q + j) * TT + ncol] = B[ks][j];
        __syncthreads();
        {
            const size_t base = ((size_t)chain * CC + c) * 4096;
            int r = tid >> 2, cb = tid & 3;
            const uint4* src = (const uint4*)(lds + r * TT + cb * 16);
            uint4* dst = (uint4*)(Pg + base + r * TT + cb * 16);
            dst[0] = src[0];
            dst[1] = src[1];
        }
        if (q == 0) Eg[(chain * CC + c) * TT + ncol] = esum;
    } else {
        if (tid == 0) out[0] = 0.f;
        const int w = tid >> 6, l = tid & 63;
        const int c = w * 16 + (l & 15);
        const int quad = l >> 4;

        const int* mp = mask + c * SS + quad * 128;
        int ls = 0;
#pragma unroll
        for (int k = 0; k < 32; ++k) {
            int4 m4i = ((const int4*)mp)[k];
            ls += m4i.x + m4i.y + m4i.z + m4i.w;
        }
        ls += __shfl_xor(ls, 16, 64);
        ls += __shfl_xor(ls, 32, 64);
        const int Lc = ls;

        const int* tb = tags + c * SS;
        const float* fc = feats + (size_t)c * SS * TT;
        float g = 0.f;
        const int t0 = quad * 128;
#pragma unroll 8
        for (int k = 0; k < 128; ++k) {
            int t = t0 + k;
            int cur = tb[t];
            int prev = (t == 0) ? START_TAG : tb[t - 1];
            if (t < Lc) g += fc[(size_t)t * TT + cur] + trans[prev * TT + cur];
        }
        if (quad == 0) g += trans[tb[Lc - 1] * TT + END_TAG];
#pragma unroll
        for (int m = 1; m < 64; m <<= 1) g += __shfl_xor(g, m, 64);
        if (l == 0) Gg[w] = g;
    }
}

__global__ __launch_bounds__(64, 1)
void crf_combine(const float* __restrict__ feats, const float* __restrict__ trans,
                 const unsigned short* __restrict__ Pg, const int* __restrict__ Eg,
                 const float* __restrict__ Gg, float* __restrict__ out) {
    __shared__ __align__(16) float yl[TT];
    const int chain = blockIdx.x;
    const int j = threadIdx.x;

    float part0 = feats[(size_t)chain * SS * TT + j] + trans[START_TAG * TT + j];
    float M0 = part0;
#pragma unroll
    for (int m = 1; m < 64; m <<= 1) M0 = fmaxf(M0, __shfl_xor(M0, m, 64));
    float x = exp2f((part0 - M0) * LOG2E_F);
    int esumX = 0;

    for (int c = 0; c < CC; ++c) {
        int e = Eg[(chain * CC + c) * TT + j];
        // FIX: max-shift the per-column exponents; never materialize 2^e.
        int emax = e;
#pragma unroll
        for (int m = 1; m < 64; m <<= 1) emax = max(emax, __shfl_xor(emax, m, 64));
        yl[j] = ldexpf(x, e - emax);   // <= 0 shift: no overflow
        float yv[64];
        {
            const uint4* yq = (const uint4*)yl;
#pragma unroll
            for (int i = 0; i < 16; ++i) {
                union { uint4 u; float f[4]; } cv;
                cv.u = yq[i];
                yv[4 * i + 0] = cv.f[0]; yv[4 * i + 1] = cv.f[1];
                yv[4 * i + 2] = cv.f[2]; yv[4 * i + 3] = cv.f[3];
            }
        }
        const uint4* rp = (const uint4*)(Pg + ((size_t)chain * CC + c) * 4096 + (size_t)j * TT);
        float acc = 0.f;
#pragma unroll
        for (int i = 0; i < 8; ++i) {
            union { uint4 u; _Float16 h[8]; } pv;
            pv.u = rp[i];
#pragma unroll
            for (int k2 = 0; k2 < 8; ++k2)
                acc = __builtin_fmaf((float)pv.h[k2], yv[8 * i + k2], acc);
        }
        // renorm by the wave-max exponent of acc (robust, exact)
        float am = acc;
#pragma unroll
        for (int m = 1; m < 64; m <<= 1) am = fmaxf(am, __shfl_xor(am, m, 64));
        int e0 = (int)((__float_as_uint(am) >> 23) & 255u) - 127;
        x = ldexpf(acc, -e0);
        esumX += e0 + emax;
    }

    float val = x * expf(trans[j * TT + END_TAG]);
#pragma unroll
    for (int m = 1; m < 64; m <<= 1) val += __shfl_xor(val, m, 64);
    float fwd = logf(val) + (float)esumX * LN2_F + M0;
    if (j == 0) {
        atomicAdd(out, fwd);
        if (chain == 0) atomicAdd(out, -(Gg[0] + Gg[1] + Gg[2] + Gg[3]));
    }
}

// ====================== fallback path (round-4, proven) ======================

__global__ void zero_out_kernel(float* __restrict__ out) { out[0] = 0.f; }

__global__ __launch_bounds__(256, 1)
void crf_chain_kernel(const float* __restrict__ feats,
                      const float* __restrict__ trans,
                      const int* __restrict__ mask,
                      const int* __restrict__ tags,
                      float* __restrict__ out) {
    const int b   = blockIdx.x;
    const int tid = threadIdx.x;
    const int w   = tid >> 6;
    const int l   = tid & 63;
    const int sub = l & 3;
    const int jl  = (w << 4) | (l >> 2);

    __shared__ __align__(16) float q[2][TT];

    const float* fb   = feats + (size_t)b * SS * TT;
    const int*   tagb = tags + b * SS;
    const int*   mkb  = mask + b * SS;

    v2f Ep[8];
    {
        const int i0 = 16 * sub;
#pragma unroll
        for (int m = 0; m < 8; ++m) {
            v2f e2;
            e2[0] = expf(trans[(i0 + 2 * m) * TT + jl]);
            e2[1] = expf(trans[(i0 + 2 * m + 1) * TT + jl]);
            Ep[m] = e2;
        }
    }

    int msum = 0;
#pragma unroll
    for (int k = 0; k < SS / 64; ++k) msum += mkb[k * 64 + l];
#pragma unroll
    for (int s_ = 1; s_ < 64; s_ <<= 1) msum += __shfl_xor(msum, s_, 64);
    const int L = msum;

    float gacc = 0.f;
    float M0 = 0.f;
    if (w == 0) {
#pragma unroll
        for (int k = 0; k < SS / 64; ++k) {
            int t = k * 64 + l;
            int cur  = tagb[t];
            int prev = (t == 0) ? START_TAG : tagb[t - 1];
            float em = fb[t * TT + cur];
            float tr = trans[prev * TT + cur];
            if (t < L) gacc += em + tr;
        }
        if (l == 0) gacc += trans[tagb[L - 1] * TT + END_TAG];
#pragma unroll
        for (int s_ = 1; s_ < 64; s_ <<= 1) gacc += __shfl_xor(gacc, s_, 64);

        float part0 = fb[l] + trans[START_TAG * TT + l];
        M0 = part0;
#pragma unroll
        for (int s_ = 1; s_ < 64; s_ <<= 1) M0 = fmaxf(M0, __shfl_xor(M0, s_, 64));
        q[0][l] = exp2f((part0 - M0) * LOG2E_F);
    }

    float fraw[8];
#pragma unroll
    for (int k = 0; k < 8; ++k) {
        int tp = 1 + k; tp = tp < SS ? tp : SS - 1;
        fraw[k] = fb[tp * TT + jl];
    }

    __syncthreads();

    int esum = 0;

#define CRF_STEP4(K, P)                                                        \
    {                                                                          \
        float qref = q[P][0];                                                  \
        const v4f* qv = (const v4f*)q[P];                                      \
        v4f r0 = qv[4 * sub + 0];                                              \
        v4f r1 = qv[4 * sub + 1];                                              \
        v4f r2 = qv[4 * sub + 2];                                              \
        v4f r3 = qv[4 * sub + 3];                                              \
        float em = exp2f(fcur[K] * LOG2E_F);                                   \
        v2f a0 = {0.f, 0.f}, a1 = {0.f, 0.f};                                  \
        v2f p;                                                                 \
        p[0] = r0.x; p[1] = r0.y; a0 = __builtin_elementwise_fma(p, Ep[0], a0);\
        p[0] = r0.z; p[1] = r0.w; a1 = __builtin_elementwise_fma(p, Ep[1], a1);\
        p[0] = r1.x; p[1] = r1.y; a0 = __builtin_elementwise_fma(p, Ep[2], a0);\
        p[0] = r1.z; p[1] = r1.w; a1 = __builtin_elementwise_fma(p, Ep[3], a1);\
        p[0] = r2.x; p[1] = r2.y; a0 = __builtin_elementwise_fma(p, Ep[4], a0);\
        p[0] = r2.z; p[1] = r2.w; a1 = __builtin_elementwise_fma(p, Ep[5], a1);\
        p[0] = r3.x; p[1] = r3.y; a0 = __builtin_elementwise_fma(p, Ep[6], a0);\
        p[0] = r3.z; p[1] = r3.w; a1 = __builtin_elementwise_fma(p, Ep[7], a1);\
        v2f sv = a0 + a1;                                                      \
        float s = sv[0] + sv[1];                                               \
        s += __shfl_xor(s, 1, 64);                                             \
        s += __shfl_xor(s, 2, 64);                                             \
        unsigned u = __float_as_uint(qref);                                    \
        int e = (int)((u >> 23) & 255u) - 127;                                 \
        esum += e;                                                             \
        float sc = __uint_as_float((unsigned)(127 - e) << 23);                 \
        float qn = s * (em * sc);                                              \
        if (sub == 0) q[1 - (P)][jl] = qn;                                     \
        __syncthreads();                                                       \
    }

    int t = 1;
    for (; t + 7 < L; t += 8) {
        float fcur[8];
#pragma unroll
        for (int k = 0; k < 8; ++k) fcur[k] = fraw[k];
#pragma unroll
        for (int k = 0; k < 8; ++k) {
            int tn = t + 8 + k; tn = tn < SS ? tn : SS - 1;
            fraw[k] = fb[tn * TT + jl];
        }
        CRF_STEP4(0, 0) CRF_STEP4(1, 1) CRF_STEP4(2, 0) CRF_STEP4(3, 1)
        CRF_STEP4(4, 0) CRF_STEP4(5, 1) CRF_STEP4(6, 0) CRF_STEP4(7, 1)
    }
    {
        float fcur[8];
#pragma unroll
        for (int k = 0; k < 8; ++k) fcur[k] = fraw[k];
        if (t < L) { CRF_STEP4(0, 0) ++t; }
        if (t < L) { CRF_STEP4(1, 1) ++t; }
        if (t < L) { CRF_STEP4(2, 0) ++t; }
        if (t < L) { CRF_STEP4(3, 1) ++t; }
        if (t < L) { CRF_STEP4(4, 0) ++t; }
        if (t < L) { CRF_STEP4(5, 1) ++t; }
        if (t < L) { CRF_STEP4(6, 0) ++t; }
    }
#undef CRF_STEP4

    if (w == 3) {
        const v4f* qv = (const v4f*)q[(L - 1) & 1];
        v4f r0 = qv[4 * sub + 0];
        v4f r1 = qv[4 * sub + 1];
        v4f r2 = qv[4 * sub + 2];
        v4f r3 = qv[4 * sub + 3];
        v2f a0 = {0.f, 0.f}, a1 = {0.f, 0.f};
        v2f p;
        p[0] = r0.x; p[1] = r0.y; a0 = __builtin_elementwise_fma(p, Ep[0], a0);
        p[0] = r0.z; p[1] = r0.w; a1 = __builtin_elementwise_fma(p, Ep[1], a1);
        p[0] = r1.x; p[1] = r1.y; a0 = __builtin_elementwise_fma(p, Ep[2], a0);
        p[0] = r1.z; p[1] = r1.w; a1 = __builtin_elementwise_fma(p, Ep[3], a1);
        p[0] = r2.x; p[1] = r2.y; a0 = __builtin_elementwise_fma(p, Ep[4], a0);
        p[0] = r2.z; p[1] = r2.w; a1 = __builtin_elementwise_fma(p, Ep[5], a1);
        p[0] = r3.x; p[1] = r3.y; a0 = __builtin_elementwise_fma(p, Ep[6], a0);
        p[0] = r3.z; p[1] = r3.w; a1 = __builtin_elementwise_fma(p, Ep[7], a1);
        v2f sv = a0 + a1;
        float s = sv[0] + sv[1];
        s += __shfl_xor(s, 1, 64);
        s += __shfl_xor(s, 2, 64);
        if (l == 60) atomicAdd(out, logf(s) + (float)esum * LN2_F);
    }
    if (w == 0 && l == 0) atomicAdd(out, M0 - gacc);
}

extern "C" void kernel_launch(void* const* d_in, const int* in_sizes, int n_in,
                              void* d_out, int out_size, void* d_ws, size_t ws_size,
                              hipStream_t stream) {
    const float* feats = (const float*)d_in[0];
    const float* trans = (const float*)d_in[1];
    const int*   mask  = (const int*)d_in[2];
    const int*   tags  = (const int*)d_in[3];
    float* out = (float*)d_out;

    if (ws_size >= (size_t)WS_NEEDED) {
        unsigned short* Pg = (unsigned short*)d_ws;
        int*   Eg = (int*)((char*)d_ws + WS_ECOL_OFF);
        float* Gg = (float*)((char*)d_ws + WS_GOLD_OFF);
        crf_chunks<<<dim3(64 * CC + 1), dim3(256), 0, stream>>>(feats, trans, mask, tags,
                                                                out, Pg, Eg, Gg);
        crf_combine<<<dim3(64), dim3(64), 0, stream>>>(feats, trans, Pg, Eg, Gg, out);
    } else {
        zero_out_kernel<<<dim3(1), dim3(1), 0, stream>>>(out);
        crf_chain_kernel<<<dim3(64), dim3(256), 0, stream>>>(feats, trans, mask, tags, out);
    }
}

// Round 9
// 153.721 us; speedup vs baseline: 1.9562x; 1.0481x over previous
//
#include <hip/hip_runtime.h>

// CRF NLL on MI355X — round 9: chunked matrix-product scan, short-chain step.
// Same algorithm as r8 (C=8 chunks of 64 steps; 64x64 f16 partial products via
// MFMA zero-copy D->B identity; combine folds chunks per chain).
// Step changes vs r8:
//   - esc feedback via readfirstlane (no max tree / ds_swizzle on the chain)
//   - em = exp2(f) computed ONCE per row per step (1 exp/lane), staged in a
//     per-wave LDS ring (depth 2), read back as broadcast ds_read_b128
//   - MFMA accumulation depth 2+2 with fp32 add (was 4-deep)
//   - sc (2^-esc) applied as separate mul; em exp2 fully off the chain

#define SS 512
#define TT 64
#define CC 8
#define KCH 64
#define START_TAG 62
#define END_TAG 63
#define LOG2E_F 1.44269504088896340736f
#define LN2_F 0.69314718055994530942f

#define WS_ECOL_OFF 4194304
#define WS_GOLD_OFF 4325376

typedef float v4f __attribute__((ext_vector_type(4)));
typedef _Float16 h4 __attribute__((ext_vector_type(4)));
typedef __fp16 c2 __attribute__((ext_vector_type(2)));
union H4u { h4 v; struct { c2 lo, hi; } p; };

__device__ __forceinline__ void cstep(const h4 (&A)[4][4], h4 (&B)[4],
                                      float* __restrict__ emb,   // &em_sh[w][P][0]
                                      float& fq, const float* __restrict__ fcol,
                                      int tload, int q, int l,
                                      int& esum, int& esc) {
    // ---- matvec: depth-2 MFMA chains + fp32 add ----
    v4f z = {0.f, 0.f, 0.f, 0.f};
    v4f D[4];
#pragma unroll
    for (int mt = 0; mt < 4; ++mt) {
        v4f a = __builtin_amdgcn_mfma_f32_16x16x16f16(A[mt][0], B[0], z, 0, 0, 0);
        a = __builtin_amdgcn_mfma_f32_16x16x16f16(A[mt][1], B[1], a, 0, 0, 0);
        v4f b = __builtin_amdgcn_mfma_f32_16x16x16f16(A[mt][2], B[2], z, 0, 0, 0);
        b = __builtin_amdgcn_mfma_f32_16x16x16f16(A[mt][3], B[3], b, 0, 0, 0);
        D[mt] = a + b;
    }
    // ---- em for THIS step: broadcast b128 reads (rows 16mt+4q..+3) ----
    v4f em[4];
#pragma unroll
    for (int mt = 0; mt < 4; ++mt) em[mt] = *(const v4f*)(emb + 16 * mt + 4 * q);
    // ---- pipeline: em for step s+2 into the SAME parity buffer (after reads) ----
    emb[l] = __builtin_amdgcn_exp2f(fq * LOG2E_F);
    fq = fcol[(size_t)tload * TT];   // raw f for step s+4 (2-step lead)
    // ---- apply em and exact power-of-2 renorm (esc from prev step) ----
    esum += esc;
    float scf = __uint_as_float((unsigned)(127 - esc) << 23);
    v4f qs[4];
#pragma unroll
    for (int mt = 0; mt < 4; ++mt) qs[mt] = D[mt] * (em[mt] * scf);
    // ---- pack: D tile mt IS next B slab ks=mt (zero-copy identity) ----
#pragma unroll
    for (int mt = 0; mt < 4; ++mt) {
        H4u u;
        u.p.lo = __builtin_amdgcn_cvt_pkrtz(qs[mt].x, qs[mt].y);
        u.p.hi = __builtin_amdgcn_cvt_pkrtz(qs[mt].z, qs[mt].w);
        B[mt] = u.v;
    }
    // ---- feedback: wave-uniform esc from one representative entry ----
    unsigned u0 = (unsigned)__builtin_amdgcn_readfirstlane((int)__float_as_uint(qs[0].x));
    esc = (int)((u0 >> 23) & 255u) - 127;
}

__global__ __launch_bounds__(256, 1)
void crf_chunks(const float* __restrict__ feats, const float* __restrict__ trans,
                const int* __restrict__ mask, const int* __restrict__ tags,
                float* __restrict__ out, unsigned short* __restrict__ Pg,
                int* __restrict__ Eg, float* __restrict__ Gg) {
    __shared__ __align__(16) float em_sh[4][2][TT];
    __shared__ __align__(16) _Float16 lds[TT * TT];
    const int blk = blockIdx.x;
    const int tid = threadIdx.x;

    if (blk < 64 * CC) {
        const int chain = blk >> 3, c = blk & 7;
        const int w = tid >> 6, l = tid & 63;
        const int n16 = l & 15, q = l >> 4;
        const int ncol = 16 * w + n16;

        // A = E^T stationary frags (row mapping verified r6/r8: row = 16mt+4q+r)
        h4 A[4][4];
#pragma unroll
        for (int mt = 0; mt < 4; ++mt)
#pragma unroll
            for (int ks = 0; ks < 4; ++ks) {
                h4 a;
#pragma unroll
                for (int e = 0; e < 4; ++e)
                    a[e] = (_Float16)expf(trans[(16 * ks + 4 * q + e) * TT + 16 * mt + n16]);
                A[mt][ks] = a;
            }

        // chain length L
        const int* mp = mask + chain * SS;
        int msum = 0;
#pragma unroll
        for (int k = 0; k < 8; ++k) msum += mp[k * 64 + l];
#pragma unroll
        for (int s_ = 1; s_ < 64; s_ <<= 1) msum += __shfl_xor(msum, s_, 64);
        const int L = msum;

        const int t0 = 1 + KCH * c;
        int nlive = (L - 1) - KCH * c;
        nlive = nlive < 0 ? 0 : (nlive > KCH ? KCH : nlive);

        // B init = identity slab
        h4 B[4];
#pragma unroll
        for (int ks = 0; ks < 4; ++ks) {
            h4 b;
#pragma unroll
            for (int j = 0; j < 4; ++j)
                b[j] = (_Float16)((16 * ks + 4 * q + j == ncol) ? 1.f : 0.f);
            B[ks] = b;
        }

        // emission pipeline prologue: em for steps t0, t0+1; raw f for +2, +3
        const float* fcol = feats + (size_t)chain * SS * TT + l;
        {
            int ta = t0 < SS ? t0 : SS - 1;
            int tb = t0 + 1 < SS ? t0 + 1 : SS - 1;
            em_sh[w][0][l] = __builtin_amdgcn_exp2f(fcol[(size_t)ta * TT] * LOG2E_F);
            em_sh[w][1][l] = __builtin_amdgcn_exp2f(fcol[(size_t)tb * TT] * LOG2E_F);
        }
        int tc = t0 + 2 < SS ? t0 + 2 : SS - 1;
        int td = t0 + 3 < SS ? t0 + 3 : SS - 1;
        float fq0 = fcol[(size_t)tc * TT];
        float fq1 = fcol[(size_t)td * TT];

        int esum = 0, esc = 0;
        int s = 0;
        for (; s + 1 < nlive; s += 2) {
            int tl0 = t0 + s + 4 < SS ? t0 + s + 4 : SS - 1;
            int tl1 = t0 + s + 5 < SS ? t0 + s + 5 : SS - 1;
            cstep(A, B, &em_sh[w][0][0], fq0, fcol, tl0, q, l, esum, esc);
            cstep(A, B, &em_sh[w][1][0], fq1, fcol, tl1, q, l, esum, esc);
        }
        if (s < nlive)
            cstep(A, B, &em_sh[w][0][0], fq0, fcol, SS - 1, q, l, esum, esc);

        // epilogue: LDS transpose to row-major, coalesced global store
#pragma unroll
        for (int ks = 0; ks < 4; ++ks)
#pragma unroll
            for (int j = 0; j < 4; ++j)
                lds[(16 * ks + 4 * q + j) * TT + ncol] = B[ks][j];
        __syncthreads();
        {
            const size_t base = ((size_t)chain * CC + c) * 4096;
            int r = tid >> 2, cb = tid & 3;
            const uint4* src = (const uint4*)(lds + r * TT + cb * 16);
            uint4* dst = (uint4*)(Pg + base + r * TT + cb * 16);
            dst[0] = src[0];
            dst[1] = src[1];
        }
        if (q == 0) Eg[(chain * CC + c) * TT + ncol] = esum;
    } else {
        // aux block: zero out + gold score
        if (tid == 0) out[0] = 0.f;
        const int w = tid >> 6, l = tid & 63;
        const int c = w * 16 + (l & 15);
        const int quad = l >> 4;

        const int* mp = mask + c * SS + quad * 128;
        int ls = 0;
#pragma unroll
        for (int k = 0; k < 32; ++k) {
            int4 m4i = ((const int4*)mp)[k];
            ls += m4i.x + m4i.y + m4i.z + m4i.w;
        }
        ls += __shfl_xor(ls, 16, 64);
        ls += __shfl_xor(ls, 32, 64);
        const int Lc = ls;

        const int* tb = tags + c * SS;
        const float* fc = feats + (size_t)c * SS * TT;
        float g = 0.f;
        const int t0 = quad * 128;
#pragma unroll 8
        for (int k = 0; k < 128; ++k) {
            int t = t0 + k;
            int cur = tb[t];
            int prev = (t == 0) ? START_TAG : tb[t - 1];
            if (t < Lc) g += fc[(size_t)t * TT + cur] + trans[prev * TT + cur];
        }
        if (quad == 0) g += trans[tb[Lc - 1] * TT + END_TAG];
#pragma unroll
        for (int m = 1; m < 64; m <<= 1) g += __shfl_xor(g, m, 64);
        if (l == 0) Gg[w] = g;
    }
}

__global__ __launch_bounds__(64, 1)
void crf_combine(const float* __restrict__ feats, const float* __restrict__ trans,
                 const unsigned short* __restrict__ Pg, const int* __restrict__ Eg,
                 const float* __restrict__ Gg, float* __restrict__ out) {
    __shared__ __align__(16) float yl[TT];
    const int chain = blockIdx.x;
    const int j = threadIdx.x;

    float part0 = feats[(size_t)chain * SS * TT + j] + trans[START_TAG * TT + j];
    float M0 = part0;
#pragma unroll
    for (int m = 1; m < 64; m <<= 1) M0 = fmaxf(M0, __shfl_xor(M0, m, 64));
    float x = exp2f((part0 - M0) * LOG2E_F);
    int esumX = 0;

    for (int c = 0; c < CC; ++c) {
        int e = Eg[(chain * CC + c) * TT + j];
        int emax = e;
#pragma unroll
        for (int m = 1; m < 64; m <<= 1) emax = max(emax, __shfl_xor(emax, m, 64));
        yl[j] = ldexpf(x, e - emax);   // <= 0 shift: no overflow
        float yv[64];
        {
            const uint4* yq = (const uint4*)yl;
#pragma unroll
            for (int i = 0; i < 16; ++i) {
                union { uint4 u; float f[4]; } cv;
                cv.u = yq[i];
                yv[4 * i + 0] = cv.f[0]; yv[4 * i + 1] = cv.f[1];
                yv[4 * i + 2] = cv.f[2]; yv[4 * i + 3] = cv.f[3];
            }
        }
        const uint4* rp = (const uint4*)(Pg + ((size_t)chain * CC + c) * 4096 + (size_t)j * TT);
        float acc = 0.f;
#pragma unroll
        for (int i = 0; i < 8; ++i) {
            union { uint4 u; _Float16 h[8]; } pv;
            pv.u = rp[i];
#pragma unroll
            for (int k2 = 0; k2 < 8; ++k2)
                acc = __builtin_fmaf((float)pv.h[k2], yv[8 * i + k2], acc);
        }
        float am = acc;
#pragma unroll
        for (int m = 1; m < 64; m <<= 1) am = fmaxf(am, __shfl_xor(am, m, 64));
        int e0 = (int)((__float_as_uint(am) >> 23) & 255u) - 127;
        x = ldexpf(acc, -e0);
        esumX += e0 + emax;
    }

    float val = x * expf(trans[j * TT + END_TAG]);
#pragma unroll
    for (int m = 1; m < 64; m <<= 1) val += __shfl_xor(val, m, 64);
    float fwd = logf(val) + (float)esumX * LN2_F + M0;
    if (j == 0) {
        atomicAdd(out, fwd);
        if (chain == 0) atomicAdd(out, -(Gg[0] + Gg[1] + Gg[2] + Gg[3]));
    }
}

extern "C" void kernel_launch(void* const* d_in, const int* in_sizes, int n_in,
                              void* d_out, int out_size, void* d_ws, size_t ws_size,
                              hipStream_t stream) {
    const float* feats = (const float*)d_in[0];
    const float* trans = (const float*)d_in[1];
    const int*   mask  = (const int*)d_in[2];
    const int*   tags  = (const int*)d_in[3];
    float* out = (float*)d_out;
    unsigned short* Pg = (unsigned short*)d_ws;
    int*   Eg = (int*)((char*)d_ws + WS_ECOL_OFF);
    float* Gg = (float*)((char*)d_ws + WS_GOLD_OFF);

    crf_chunks<<<dim3(64 * CC + 1), dim3(256), 0, stream>>>(feats, trans, mask, tags,
                                                            out, Pg, Eg, Gg);
    crf_combine<<<dim3(64), dim3(64), 0, stream>>>(feats, trans, Pg, Eg, Gg, out);
}

// Round 10
// 112.056 us; speedup vs baseline: 2.6836x; 1.3718x over previous
//
#include <hip/hip_runtime.h>

// CRF NLL on MI355X — round 10: chunked scan, 2x ILP + in-block merge.
// Each chunk (64 steps) = two independent 32-step half-products Ha, Hb
// advanced interleaved in the same wave (two dependency chains in flight),
// then merged in-block: R = Hb * Ha via one 64x64x64 MFMA matmul (Hb
// renormalized to block-uniform exponent, A-frags via padded LDS).
// prep kernel: gold score (64-block parallel), E=exp(trans) precompute, zero.

#define SS 512
#define TT 64
#define CC 8
#define KCH 64
#define START_TAG 62
#define END_TAG 63
#define LOG2E_F 1.44269504088896340736f
#define LN2_F 0.69314718055994530942f

#define WS_ECOL_OFF 4194304
#define WS_GOLD_OFF 4325376
#define WS_EF_OFF   4325632
#define MSTR 72   // merge-LDS row stride in halfs (16B-aligned rows, bank-spread)

typedef float v4f __attribute__((ext_vector_type(4)));
typedef _Float16 h4 __attribute__((ext_vector_type(4)));
typedef __fp16 c2 __attribute__((ext_vector_type(2)));
union H4u { h4 v; struct { c2 lo, hi; } p; };

// ---------------- prep: gold score + E precompute + zero ----------------
__global__ __launch_bounds__(256, 1)
void crf_prep(const float* __restrict__ feats, const float* __restrict__ trans,
              const int* __restrict__ mask, const int* __restrict__ tags,
              float* __restrict__ out, float* __restrict__ Gg,
              _Float16* __restrict__ Ef) {
    const int c = blockIdx.x;
    const int tid = threadIdx.x;
    const int w = tid >> 6;
    __shared__ int li[4];
    __shared__ float gf[4];
    __shared__ int Lsh;

    int m = mask[c * SS + tid] + mask[c * SS + 256 + tid];
#pragma unroll
    for (int s_ = 1; s_ < 64; s_ <<= 1) m += __shfl_xor(m, s_, 64);
    if ((tid & 63) == 0) li[w] = m;
    __syncthreads();
    if (tid == 0) Lsh = li[0] + li[1] + li[2] + li[3];
    __syncthreads();
    const int Lc = Lsh;

    float g = 0.f;
#pragma unroll
    for (int rep = 0; rep < 2; ++rep) {
        int t = tid + rep * 256;
        if (t < Lc) {
            int cur = tags[c * SS + t];
            int prev = (t == 0) ? START_TAG : tags[c * SS + t - 1];
            g += feats[(size_t)c * SS * TT + (size_t)t * TT + cur] + trans[prev * TT + cur];
        }
    }
    if (tid == 0) g += trans[tags[c * SS + Lc - 1] * TT + END_TAG];
#pragma unroll
    for (int s_ = 1; s_ < 64; s_ <<= 1) g += __shfl_xor(g, s_, 64);
    if ((tid & 63) == 0) gf[w] = g;
    __syncthreads();
    if (tid == 0) Gg[c] = gf[0] + gf[1] + gf[2] + gf[3];

    if (c == 0) {
#pragma unroll
        for (int k = 0; k < 16; ++k) {
            int idx = tid + k * 256;
            Ef[idx] = (_Float16)expf(trans[idx]);
        }
        if (tid == 0) out[0] = 0.f;
    }
}

// ---------------- per-step core (r9-proven) ----------------
__device__ __forceinline__ void cstep(const h4 (&A)[4][4], h4 (&B)[4],
                                      float* __restrict__ emb, float& fq,
                                      const float* __restrict__ fcol, int tload,
                                      int q, int l, int& esum, int& esc) {
    v4f z = {0.f, 0.f, 0.f, 0.f};
    v4f D[4];
#pragma unroll
    for (int mt = 0; mt < 4; ++mt) {
        v4f a = __builtin_amdgcn_mfma_f32_16x16x16f16(A[mt][0], B[0], z, 0, 0, 0);
        a = __builtin_amdgcn_mfma_f32_16x16x16f16(A[mt][1], B[1], a, 0, 0, 0);
        v4f b = __builtin_amdgcn_mfma_f32_16x16x16f16(A[mt][2], B[2], z, 0, 0, 0);
        b = __builtin_amdgcn_mfma_f32_16x16x16f16(A[mt][3], B[3], b, 0, 0, 0);
        D[mt] = a + b;
    }
    v4f em[4];
#pragma unroll
    for (int mt = 0; mt < 4; ++mt) em[mt] = *(const v4f*)(emb + 16 * mt + 4 * q);
    emb[l] = __builtin_amdgcn_exp2f(fq * LOG2E_F);
    fq = fcol[(size_t)tload * TT];
    esum += esc;
    float scf = __uint_as_float((unsigned)(127 - esc) << 23);
    v4f qs[4];
#pragma unroll
    for (int mt = 0; mt < 4; ++mt) qs[mt] = D[mt] * (em[mt] * scf);
#pragma unroll
    for (int mt = 0; mt < 4; ++mt) {
        H4u u;
        u.p.lo = __builtin_amdgcn_cvt_pkrtz(qs[mt].x, qs[mt].y);
        u.p.hi = __builtin_amdgcn_cvt_pkrtz(qs[mt].z, qs[mt].w);
        B[mt] = u.v;
    }
    unsigned u0 = (unsigned)__builtin_amdgcn_readfirstlane((int)__float_as_uint(qs[0].x));
    esc = (int)((u0 >> 23) & 255u) - 127;
}

// ---------------- chunk kernel ----------------
__global__ __launch_bounds__(256, 1)
void crf_chunks(const float* __restrict__ feats, const int* __restrict__ mask,
                const _Float16* __restrict__ Ef, unsigned short* __restrict__ Pg,
                int* __restrict__ Eg) {
    __shared__ float emA[4][2][TT];
    __shared__ float emB[4][2][TT];
    __shared__ __align__(16) _Float16 mld[TT * MSTR];
    __shared__ int ebuf[4];

    const int blk = blockIdx.x;
    const int chain = blk >> 3, c = blk & 7;
    const int tid = threadIdx.x;
    const int w = tid >> 6, l = tid & 63;
    const int n16 = l & 15, q = l >> 4;
    const int ncol = 16 * w + n16;

    // A = E^T stationary frags from precomputed Ef
    h4 A[4][4];
#pragma unroll
    for (int mt = 0; mt < 4; ++mt)
#pragma unroll
        for (int ks = 0; ks < 4; ++ks) {
            h4 a;
#pragma unroll
            for (int e = 0; e < 4; ++e)
                a[e] = Ef[(16 * ks + 4 * q + e) * TT + 16 * mt + n16];
            A[mt][ks] = a;
        }

    // chain length L
    const int* mp = mask + chain * SS;
    int msum = 0;
#pragma unroll
    for (int k = 0; k < 8; ++k) msum += mp[k * 64 + l];
#pragma unroll
    for (int s_ = 1; s_ < 64; s_ <<= 1) msum += __shfl_xor(msum, s_, 64);
    const int L = msum;

    const int t0a = 1 + KCH * c;
    const int t0b = t0a + 32;
    int nliveA = (L - 1) - KCH * c;
    nliveA = nliveA < 0 ? 0 : (nliveA > 32 ? 32 : nliveA);
    int nliveB = (L - 1) - KCH * c - 32;
    nliveB = nliveB < 0 ? 0 : (nliveB > 32 ? 32 : nliveB);

    // identity inits
    h4 BA[4], BB[4];
#pragma unroll
    for (int ks = 0; ks < 4; ++ks) {
        h4 b;
#pragma unroll
        for (int j = 0; j < 4; ++j)
            b[j] = (_Float16)((16 * ks + 4 * q + j == ncol) ? 1.f : 0.f);
        BA[ks] = b;
        BB[ks] = b;
    }

    // emission pipelines (per sub-chain), 2-step lead
    const float* fcol = feats + (size_t)chain * SS * TT + l;
#define CLAMP_T(x) ((x) < SS ? (x) : SS - 1)
    emA[w][0][l] = __builtin_amdgcn_exp2f(fcol[(size_t)CLAMP_T(t0a) * TT] * LOG2E_F);
    emA[w][1][l] = __builtin_amdgcn_exp2f(fcol[(size_t)CLAMP_T(t0a + 1) * TT] * LOG2E_F);
    emB[w][0][l] = __builtin_amdgcn_exp2f(fcol[(size_t)CLAMP_T(t0b) * TT] * LOG2E_F);
    emB[w][1][l] = __builtin_amdgcn_exp2f(fcol[(size_t)CLAMP_T(t0b + 1) * TT] * LOG2E_F);
    float fqA0 = fcol[(size_t)CLAMP_T(t0a + 2) * TT];
    float fqA1 = fcol[(size_t)CLAMP_T(t0a + 3) * TT];
    float fqB0 = fcol[(size_t)CLAMP_T(t0b + 2) * TT];
    float fqB1 = fcol[(size_t)CLAMP_T(t0b + 3) * TT];

    int esumA = 0, escA = 0, esumB = 0, escB = 0;

    const int nB2 = nliveB & ~1;
    int s = 0;
    for (; s < nB2; s += 2) {
        cstep(A, BA, &emA[w][0][0], fqA0, fcol, CLAMP_T(t0a + s + 4), q, l, esumA, escA);
        cstep(A, BB, &emB[w][0][0], fqB0, fcol, CLAMP_T(t0b + s + 4), q, l, esumB, escB);
        cstep(A, BA, &emA[w][1][0], fqA1, fcol, CLAMP_T(t0a + s + 5), q, l, esumA, escA);
        cstep(A, BB, &emB[w][1][0], fqB1, fcol, CLAMP_T(t0b + s + 5), q, l, esumB, escB);
    }
    if (nliveB & 1)
        cstep(A, BB, &emB[w][0][0], fqB0, fcol, SS - 1, q, l, esumB, escB);
    for (; s + 1 < nliveA; s += 2) {
        cstep(A, BA, &emA[w][0][0], fqA0, fcol, CLAMP_T(t0a + s + 4), q, l, esumA, escA);
        cstep(A, BA, &emA[w][1][0], fqA1, fcol, CLAMP_T(t0a + s + 5), q, l, esumA, escA);
    }
    if (s < nliveA)
        cstep(A, BA, &emA[w][0][0], fqA0, fcol, SS - 1, q, l, esumA, escA);
#undef CLAMP_T

    // ---- merge: R = Hb * Ha ----
    if (l == 0) ebuf[w] = esumB;
    __syncthreads();
    int eBmax = max(max(ebuf[0], ebuf[1]), max(ebuf[2], ebuf[3]));
    {
        _Float16 scl = (_Float16)ldexpf(1.f, esumB - eBmax);  // <=1, exact pow2
        h4 s4 = {scl, scl, scl, scl};
#pragma unroll
        for (int ks = 0; ks < 4; ++ks) {
            h4 v = BB[ks] * s4;
#pragma unroll
            for (int j = 0; j < 4; ++j)
                mld[(16 * ks + 4 * q + j) * MSTR + ncol] = v[j];
        }
    }
    __syncthreads();
    h4 AH[4][4];
#pragma unroll
    for (int mt = 0; mt < 4; ++mt)
#pragma unroll
        for (int ks = 0; ks < 4; ++ks)
            AH[mt][ks] = *(const h4*)(mld + (16 * mt + n16) * MSTR + 16 * ks + 4 * q);
    v4f z = {0.f, 0.f, 0.f, 0.f};
    h4 Rf[4];
#pragma unroll
    for (int mt = 0; mt < 4; ++mt) {
        v4f a = __builtin_amdgcn_mfma_f32_16x16x16f16(AH[mt][0], BA[0], z, 0, 0, 0);
        a = __builtin_amdgcn_mfma_f32_16x16x16f16(AH[mt][1], BA[1], a, 0, 0, 0);
        v4f b = __builtin_amdgcn_mfma_f32_16x16x16f16(AH[mt][2], BA[2], z, 0, 0, 0);
        b = __builtin_amdgcn_mfma_f32_16x16x16f16(AH[mt][3], BA[3], b, 0, 0, 0);
        v4f d = a + b;
        H4u u;
        u.p.lo = __builtin_amdgcn_cvt_pkrtz(d.x, d.y);
        u.p.hi = __builtin_amdgcn_cvt_pkrtz(d.z, d.w);
        Rf[mt] = u.v;
    }
    __syncthreads();  // done reading Hb from mld; reuse for epilogue
#pragma unroll
    for (int mt = 0; mt < 4; ++mt)
#pragma unroll
        for (int j = 0; j < 4; ++j)
            mld[(16 * mt + 4 * q + j) * MSTR + ncol] = Rf[mt][j];
    __syncthreads();
    {
        const size_t base = ((size_t)chain * CC + c) * 4096;
        int r = tid >> 2, cb = tid & 3;
        const uint4* src = (const uint4*)(mld + r * MSTR + cb * 16);
        uint4* dst = (uint4*)(Pg + base + r * TT + cb * 16);
        dst[0] = src[0];
        dst[1] = src[1];
    }
    if (q == 0) Eg[(chain * CC + c) * TT + ncol] = esumA + eBmax;
}

// ---------------- combine ----------------
__global__ __launch_bounds__(64, 1)
void crf_combine(const float* __restrict__ feats, const float* __restrict__ trans,
                 const unsigned short* __restrict__ Pg, const int* __restrict__ Eg,
                 const float* __restrict__ Gg, float* __restrict__ out) {
    __shared__ __align__(16) float yl[TT];
    const int chain = blockIdx.x;
    const int j = threadIdx.x;

    float part0 = feats[(size_t)chain * SS * TT + j] + trans[START_TAG * TT + j];
    float M0 = part0;
#pragma unroll
    for (int m = 1; m < 64; m <<= 1) M0 = fmaxf(M0, __shfl_xor(M0, m, 64));
    float x = exp2f((part0 - M0) * LOG2E_F);
    int esumX = 0;

    for (int c = 0; c < CC; ++c) {
        int e = Eg[(chain * CC + c) * TT + j];
        int emax = e;
#pragma unroll
        for (int m = 1; m < 64; m <<= 1) emax = max(emax, __shfl_xor(emax, m, 64));
        yl[j] = ldexpf(x, e - emax);
        float yv[64];
        {
            const uint4* yq = (const uint4*)yl;
#pragma unroll
            for (int i = 0; i < 16; ++i) {
                union { uint4 u; float f[4]; } cv;
                cv.u = yq[i];
                yv[4 * i + 0] = cv.f[0]; yv[4 * i + 1] = cv.f[1];
                yv[4 * i + 2] = cv.f[2]; yv[4 * i + 3] = cv.f[3];
            }
        }
        const uint4* rp = (const uint4*)(Pg + ((size_t)chain * CC + c) * 4096 + (size_t)j * TT);
        float acc = 0.f;
#pragma unroll
        for (int i = 0; i < 8; ++i) {
            union { uint4 u; _Float16 h[8]; } pv;
            pv.u = rp[i];
#pragma unroll
            for (int k2 = 0; k2 < 8; ++k2)
                acc = __builtin_fmaf((float)pv.h[k2], yv[8 * i + k2], acc);
        }
        float am = acc;
#pragma unroll
        for (int m = 1; m < 64; m <<= 1) am = fmaxf(am, __shfl_xor(am, m, 64));
        int e0 = (int)((__float_as_uint(am) >> 23) & 255u) - 127;
        x = ldexpf(acc, -e0);
        esumX += e0 + emax;
    }

    float val = x * expf(trans[j * TT + END_TAG]);
#pragma unroll
    for (int m = 1; m < 64; m <<= 1) val += __shfl_xor(val, m, 64);
    float fwd = logf(val) + (float)esumX * LN2_F + M0;
    if (j == 0) atomicAdd(out, fwd);

    if (chain == 0) {
        float gv = Gg[j];
#pragma unroll
        for (int m = 1; m < 64; m <<= 1) gv += __shfl_xor(gv, m, 64);
        if (j == 0) atomicAdd(out, -gv);
    }
}

extern "C" void kernel_launch(void* const* d_in, const int* in_sizes, int n_in,
                              void* d_out, int out_size, void* d_ws, size_t ws_size,
                              hipStream_t stream) {
    const float* feats = (const float*)d_in[0];
    const float* trans = (const float*)d_in[1];
    const int*   mask  = (const int*)d_in[2];
    const int*   tags  = (const int*)d_in[3];
    float* out = (float*)d_out;
    unsigned short* Pg = (unsigned short*)d_ws;
    int*       Eg = (int*)((char*)d_ws + WS_ECOL_OFF);
    float*     Gg = (float*)((char*)d_ws + WS_GOLD_OFF);
    _Float16*  Ef = (_Float16*)((char*)d_ws + WS_EF_OFF);

    crf_prep<<<dim3(64), dim3(256), 0, stream>>>(feats, trans, mask, tags, out, Gg, Ef);
    crf_chunks<<<dim3(64 * CC), dim3(256), 0, stream>>>(feats, mask, Ef, Pg, Eg);
    crf_combine<<<dim3(64), dim3(64), 0, stream>>>(feats, trans, Pg, Eg, Gg, out);
}